// Round 1
// baseline (36.554 us; speedup 1.0000x reference)
//
#include <hip/hip_runtime.h>

// SineSynth: B=4, S=1000 sines, F=256 frames, 32x linear upsample -> T=8192.
// out[b][t] = sum_s amp_up[b,s,t] * sin( cumsum(freq_up*2pi/FS)[t] + init[b,s] )
//
// Closed-form phase (in REVOLUTIONS, so fract() feeds v_sin_f32 directly):
//   t = 32k+16+j (k in [0,255], j in [0,32)):  w_j=(j+0.5)/32
//   base(k)   = 16*(C[k]+C[k+1])/FS + init/(2pi),  C[k]=sum_{m<k} f[m]
//   phase(j)  = base + (j+1)*f[k]/FS + (f[k+1]-f[k])*(j+1)^2/(64*FS)
//   amp(j)    = a[k] + (a[k+1]-a[k])*(j+0.5)/32
//   head t<16:  phase = (t+1)*f[0]/FS + init/(2pi), amp = a[0]
//   tail k=255: f[256]:=f[255] (quadratic term = 0), amp = a[255]

#define FS_D 44100.0
#define S_TOTAL 1000
#define FRAMES 256
#define T_OUT 8192
#define CH 8            // sines per block
#define NC 125          // chunks (8*125 = 1000 exactly)
#define BATCH 4

template <bool ATOMIC>
__global__ __launch_bounds__(256) void synth_partial(
    const float* __restrict__ freq, const float* __restrict__ amp,
    const float* __restrict__ initp, float* __restrict__ dst)
{
  __shared__ float base_lds[CH][FRAMES];
  __shared__ float head_lds[CH];

  const int b     = blockIdx.x / NC;
  const int chunk = blockIdx.x % NC;
  const int s0    = chunk * CH;
  const int tid   = threadIdx.x;
  const int lane  = tid & 63;
  const int wave  = tid >> 6;

  const double inv2pi = 0.15915494309189535;
  const double k16    = 16.0 / FS_D;

  // ---- Phase 1: per-row exclusive scan (double) -> segment base fracs ----
  for (int r = wave; r < CH; r += 4) {
    const int s = s0 + r;
    if (s < S_TOTAL) {
      const long long roff = (long long)(b * S_TOTAL + s) * FRAMES;
      const float4 fv = reinterpret_cast<const float4*>(freq + roff)[lane];
      const double f0 = fv.x, f1 = fv.y, f2 = fv.z, f3 = fv.w;
      const double tot = f0 + f1 + f2 + f3;
      double incl = tot;
      #pragma unroll
      for (int off = 1; off < 64; off <<= 1) {
        double v = __shfl_up(incl, (unsigned)off, 64);
        if (lane >= off) incl += v;
      }
      double C = incl - tot;  // exclusive prefix of frames at 4*lane
      const double initrev = (double)initp[b * S_TOTAL + s] * inv2pi;
      if (lane == 0) head_lds[r] = (float)(initrev - floor(initrev));
      const double fk[4] = {f0, f1, f2, f3};
      #pragma unroll
      for (int i = 0; i < 4; ++i) {
        const double basev = k16 * (2.0 * C + fk[i]) + initrev;
        base_lds[r][4 * lane + i] = (float)(basev - floor(basev));
        C += fk[i];
      }
    }
  }
  __syncthreads();

  // ---- Phase 2: thread k owns output segment k (32 samples) ----
  const int k = tid;                 // 0..255
  float acc[32];
  #pragma unroll
  for (int j = 0; j < 32; ++j) acc[j] = 0.f;

  const float invfs = (float)(1.0 / FS_D);

  for (int r = 0; r < CH; ++r) {
    const int s = s0 + r;
    if (s >= S_TOTAL) break;
    const long long roff = (long long)(b * S_TOTAL + s) * FRAMES;
    const float f_k  = freq[roff + k];
    const float f_k1 = (k < FRAMES - 1) ? freq[roff + k + 1] : f_k;
    const float a_k  = amp[roff + k];
    const float a_k1 = (k < FRAMES - 1) ? amp[roff + k + 1] : a_k;
    const float base = base_lds[r][k];
    const float c1 = f_k * invfs;
    const float c2 = (f_k1 - f_k) * (invfs * (1.0f / 64.0f));
    const float d1 = (a_k1 - a_k) * (1.0f / 32.0f);

    if (k < FRAMES - 1) {
      // forward differences of base + c1*u + c2*u^2, u = j+1
      float p   = base + c1 + c2;
      float dp  = c1 + 3.0f * c2;
      const float ddp = 2.0f * c2;
      float am  = fmaf(0.5f, d1, a_k);
      #pragma unroll
      for (int j = 0; j < 32; ++j) {
        const float fr = p - floorf(p);
        acc[j] = fmaf(am, __builtin_amdgcn_sinf(fr), acc[j]);
        p += dp; dp += ddp; am += d1;
      }
    } else {
      // tail t = 8176..8191 (c2 = 0, d1 = 0 by clamping)
      float p = base + c1;
      #pragma unroll
      for (int j = 0; j < 16; ++j) {
        const float fr = p - floorf(p);
        acc[j] = fmaf(a_k, __builtin_amdgcn_sinf(fr), acc[j]);
        p += c1;
      }
      // head t = 0..15: phase = (t+1)*f0/FS + init_frac, amp = a0
      const float f0v = freq[roff];
      const float a0v = amp[roff];
      const float c1h = f0v * invfs;
      float ph = head_lds[r] + c1h;
      #pragma unroll
      for (int j = 0; j < 16; ++j) {
        const float fr = ph - floorf(ph);
        acc[16 + j] = fmaf(a0v, __builtin_amdgcn_sinf(fr), acc[16 + j]);
        ph += c1h;
      }
    }
  }

  // ---- write-out ----
  if (ATOMIC) {
    float* outb = dst + (long long)b * T_OUT;
    if (k < FRAMES - 1) {
      const int t0 = 32 * k + 16;
      #pragma unroll
      for (int j = 0; j < 32; ++j) atomicAdd(outb + t0 + j, acc[j]);
    } else {
      #pragma unroll
      for (int j = 0; j < 16; ++j) atomicAdd(outb + 8176 + j, acc[j]);
      #pragma unroll
      for (int j = 0; j < 16; ++j) atomicAdd(outb + j, acc[16 + j]);
    }
  } else {
    float* pout = dst + (long long)(b * NC + chunk) * T_OUT;
    if (k < FRAMES - 1) {
      const int t0 = 32 * k + 16;
      #pragma unroll
      for (int j = 0; j < 8; ++j) {
        reinterpret_cast<float4*>(pout + t0)[j] =
            make_float4(acc[4*j], acc[4*j+1], acc[4*j+2], acc[4*j+3]);
      }
    } else {
      #pragma unroll
      for (int j = 0; j < 4; ++j)
        reinterpret_cast<float4*>(pout + 8176)[j] =
            make_float4(acc[4*j], acc[4*j+1], acc[4*j+2], acc[4*j+3]);
      #pragma unroll
      for (int j = 0; j < 4; ++j)
        reinterpret_cast<float4*>(pout)[j] =
            make_float4(acc[16+4*j], acc[17+4*j], acc[18+4*j], acc[19+4*j]);
    }
  }
}

__global__ __launch_bounds__(256) void reduce_out(
    const float* __restrict__ partial, float* __restrict__ out)
{
  const int i = blockIdx.x * 256 + threadIdx.x;   // 0..32767
  const int b = i >> 13;
  const int t = i & (T_OUT - 1);
  const float* p = partial + (long long)(b * NC) * T_OUT + t;
  float s = 0.f;
  #pragma unroll 5
  for (int c = 0; c < NC; ++c) s += p[(long long)c * T_OUT];
  out[i] = s;
}

extern "C" void kernel_launch(void* const* d_in, const int* in_sizes, int n_in,
                              void* d_out, int out_size, void* d_ws, size_t ws_size,
                              hipStream_t stream) {
  const float* freq  = (const float*)d_in[0];
  const float* amp   = (const float*)d_in[1];
  const float* initp = (const float*)d_in[2];
  float* out = (float*)d_out;

  const size_t need_ws = (size_t)BATCH * NC * T_OUT * sizeof(float); // 16.4 MB

  if (ws_size >= need_ws) {
    float* partial = (float*)d_ws;
    synth_partial<false><<<dim3(BATCH * NC), dim3(256), 0, stream>>>(
        freq, amp, initp, partial);
    reduce_out<<<dim3((BATCH * T_OUT) / 256), dim3(256), 0, stream>>>(
        partial, out);
  } else {
    // fallback: accumulate directly into out with atomics
    hipMemsetAsync(d_out, 0, (size_t)out_size * sizeof(float), stream);
    synth_partial<true><<<dim3(BATCH * NC), dim3(256), 0, stream>>>(
        freq, amp, initp, out);
  }
}